// Round 9
// baseline (160.079 us; speedup 1.0000x reference)
//
#include <hip/hip_runtime.h>

#define SCALE 0.17677669529663687f  // 1/sqrt(32)
#define BSTR 68                     // LDS e-tile row stride (floats): 16B-aligned rows, banks spread

// ---------------------------------------------------------------------------
// Single fused flash-style kernel. One block per query row i. 512 x 512 thr.
// Prologue: q_s=(x[i]@Wq)*SCALE; qce[h][c]=q_s.We-slice, qcx[h][c]=q_s.Wk-slice
// Chunks of 64 j (8 chunks), e-tile staged regs->LDS double-buffered:
//  (A) logit[h][j] = sum_c e[i,j,c]qce + sum_c x[j,c]qcx   (e from LDS)
//  (B) online softmax per head (running m,l in wave regs), p chunk -> LDS
//  (C) ae[h,c] += p*e (LDS cols), px[h,c] += p*x; rescale by alpha
// Epilogue: /l, emb = ae@We + px@Wv (head-block), out = emb@Wo + bo
// ---------------------------------------------------------------------------
__global__ __launch_bounds__(512, 4) void fused_kernel(
    const float* __restrict__ e, const float* __restrict__ x,
    const float* __restrict__ Wq, const float* __restrict__ Wk,
    const float* __restrict__ We, const float* __restrict__ Wv,
    const float* __restrict__ Wo, const float* __restrict__ bo,
    float* __restrict__ out) {
  const int t = threadIdx.x, i = blockIdx.x;
  const int wv = t >> 6, lane = t & 63;
  const int js = t >> 3, g = t & 7, c8 = g * 8;   // staging/logits mapping

  __shared__ __align__(16) float sm[12304];
  float* bufs  = sm;            // [2][64*BSTR] e-tile double buffer (34.8 KB)
  float* qch   = sm + 8704;     // [2][8][64] coefs: (stream, h, c)
  float* s_pl  = sm + 9728;     // [64][12] chunk logits->probs; prologue: q temp [32][8]
  float* s_al  = sm + 10496;    // [8] alpha
  float* s_l   = sm + 10504;    // [8] final l
  float* s_ae  = sm + 10512;    // [512]
  float* s_px  = sm + 11024;    // [512]
  float* s_emb = sm + 11536;    // [256]
  float* s_op  = sm + 11792;    // [512]
  float* s_part = sm;           // alias of bufs: [8][1024] wave partials

  const float* gbase = e + ((size_t)i << 15);

  // ---- stage chunk 0 loads (pure loads; pipeline freely)
  float4 stA = *(const float4*)(gbase + js * 64 + c8);
  float4 stB = *(const float4*)(gbase + js * 64 + c8 + 4);

  // ---- q_s into transposed temp s_pl[d*8+h]
  if (t < 256) {
    const float* xr = x + i * 64;
    float a = 0;
#pragma unroll 8
    for (int c = 0; c < 64; ++c) a += xr[c] * Wq[c * 256 + t];
    s_pl[(t & 31) * 8 + (t >> 5)] = a * SCALE;
  }
  __syncthreads();

  // ---- coefs: thread (c=js, h=g)
  {
    const float4* wer = (const float4*)(We + js * 256 + g * 32);
    const float4* wkr = (const float4*)(Wk + js * 256 + g * 32);
    float se = 0, sk = 0;
#pragma unroll
    for (int d4 = 0; d4 < 8; ++d4) {
      float4 w1 = wer[d4], w2 = wkr[d4];
      float q0 = s_pl[(d4 * 4 + 0) * 8 + g], q1 = s_pl[(d4 * 4 + 1) * 8 + g];
      float q2 = s_pl[(d4 * 4 + 2) * 8 + g], q3 = s_pl[(d4 * 4 + 3) * 8 + g];
      se += q0 * w1.x + q1 * w1.y + q2 * w1.z + q3 * w1.w;
      sk += q0 * w2.x + q1 * w2.y + q2 * w2.z + q3 * w2.w;
    }
    qch[g * 64 + js] = se;
    qch[512 + g * 64 + js] = sk;
  }
  // ---- write chunk 0 -> buf0; issue chunk-1 loads
  {
    float* wb = bufs + js * BSTR + c8;
    *(float4*)wb = stA;
    *(float4*)(wb + 4) = stB;
  }
  stA = *(const float4*)(gbase + ((64 + js) << 6) + c8);
  stB = *(const float4*)(gbase + ((64 + js) << 6) + c8 + 4);
  __syncthreads();

  // ---- chunk loop
  float m_run = -1e30f, l_run = 0.f;
  float ae[8], px[8];
#pragma unroll
  for (int h = 0; h < 8; ++h) { ae[h] = 0.f; px[h] = 0.f; }

  for (int k = 0; k < 8; ++k) {
    const float* buf = bufs + (k & 1) * (64 * BSTR);
    float* nbuf = bufs + ((k & 1) ^ 1) * (64 * BSTR);

    // (A) logits for chunk k: thread (j=js, channel-slice g)
    {
      const float* xr = x + ((k * 64 + js) << 6) + c8;
      float4 xa = *(const float4*)xr;
      float4 xb = *(const float4*)(xr + 4);
      const float* er = buf + js * BSTR + c8;
      float4 ea = *(const float4*)er;
      float4 eb = *(const float4*)(er + 4);
      float acc[8];
#pragma unroll
      for (int h = 0; h < 8; ++h) {
        const float4* ce = (const float4*)(qch + h * 64 + c8);
        const float4* cx = (const float4*)(qch + 512 + h * 64 + c8);
        float4 c0 = ce[0], c1 = ce[1], d0 = cx[0], d1 = cx[1];
        acc[h] = ea.x * c0.x + ea.y * c0.y + ea.z * c0.z + ea.w * c0.w
               + eb.x * c1.x + eb.y * c1.y + eb.z * c1.z + eb.w * c1.w
               + xa.x * d0.x + xa.y * d0.y + xa.z * d0.z + xa.w * d0.w
               + xb.x * d1.x + xb.y * d1.y + xb.z * d1.z + xb.w * d1.w;
      }
#pragma unroll
      for (int m = 1; m <= 4; m <<= 1)
#pragma unroll
        for (int h = 0; h < 8; ++h) acc[h] += __shfl_xor(acc[h], m, 64);
      if (g == 0) {
        *(float4*)(s_pl + js * 12) = make_float4(acc[0], acc[1], acc[2], acc[3]);
        *(float4*)(s_pl + js * 12 + 4) = make_float4(acc[4], acc[5], acc[6], acc[7]);
      }
    }
    __syncthreads();

    // (B) online softmax: wave wv owns head wv; lane = chunk-local j
    {
      float lg = s_pl[lane * 12 + wv];
      float cm = lg;
#pragma unroll
      for (int off = 32; off; off >>= 1) cm = fmaxf(cm, __shfl_xor(cm, off, 64));
      float mnew = fmaxf(m_run, cm);
      float al = __expf(m_run - mnew);
      float p = __expf(lg - mnew);
      float ss = p;
#pragma unroll
      for (int off = 32; off; off >>= 1) ss += __shfl_xor(ss, off, 64);
      l_run = l_run * al + ss;
      m_run = mnew;
      s_pl[lane * 12 + wv] = p;
      if (lane == 0) s_al[wv] = al;
    }
    // stage: write chunk k+1 (regs) -> other buffer; issue chunk k+2 loads
    if (k < 7) {
      float* wb = nbuf + js * BSTR + c8;
      *(float4*)wb = stA;
      *(float4*)(wb + 4) = stB;
    }
    if (k < 6) {
      const float* gs = gbase + ((((k + 2) << 6) + js) << 6) + c8;
      stA = *(const float4*)gs;
      stB = *(const float4*)(gs + 4);
    }
    __syncthreads();

    // (C) accumulate: lane = channel c, wave wv owns 8 chunk-local j
    {
#pragma unroll
      for (int h = 0; h < 8; ++h) { float a_ = s_al[h]; ae[h] *= a_; px[h] *= a_; }
      const float* xc = x + (k << 12) + lane;
#pragma unroll
      for (int u = 0; u < 8; ++u) {
        const int jj = (wv << 3) + u;
        float ev = buf[jj * BSTR + lane];           // conflict-free columns
        float xv = xc[jj << 6];                      // coalesced, L2-hot
        float4 p0 = *(const float4*)(s_pl + jj * 12);  // uniform -> broadcast
        float4 p1 = *(const float4*)(s_pl + jj * 12 + 4);
        ae[0] += p0.x * ev; ae[1] += p0.y * ev; ae[2] += p0.z * ev; ae[3] += p0.w * ev;
        ae[4] += p1.x * ev; ae[5] += p1.y * ev; ae[6] += p1.z * ev; ae[7] += p1.w * ev;
        px[0] += p0.x * xv; px[1] += p0.y * xv; px[2] += p0.z * xv; px[3] += p0.w * xv;
        px[4] += p1.x * xv; px[5] += p1.y * xv; px[6] += p1.z * xv; px[7] += p1.w * xv;
      }
    }
    __syncthreads();
  }

  // ---- epilogue
  if (lane == 0) s_l[wv] = l_run;
#pragma unroll
  for (int h = 0; h < 8; ++h) {
    s_part[wv * 1024 + h * 64 + lane] = ae[h];
    s_part[wv * 1024 + 512 + h * 64 + lane] = px[h];
  }
  __syncthreads();
  {
    const float inv = 1.0f / s_l[t >> 6];
    float va = 0, vp = 0;
#pragma unroll
    for (int w = 0; w < 8; ++w) {
      va += s_part[w * 1024 + t];
      vp += s_part[w * 1024 + 512 + t];
    }
    s_ae[t] = va * inv;
    s_px[t] = vp * inv;
  }
  __syncthreads();
  {
    const int nd = t & 255, ch = t >> 8, hn = nd >> 5;
    float emb = 0;
    const int cb = ch * 32;
#pragma unroll 8
    for (int c = cb; c < cb + 32; ++c)
      emb += s_ae[hn * 64 + c] * We[c * 256 + nd] + s_px[hn * 64 + c] * Wv[c * 256 + nd];
    s_part[ch * 256 + nd] = emb;
  }
  __syncthreads();
  if (t < 256) s_emb[t] = s_part[t] + s_part[256 + t];
  __syncthreads();
  {
    const int o = t & 63, mc = t >> 6;
    float oo = 0;
#pragma unroll 8
    for (int m2 = mc * 32; m2 < mc * 32 + 32; ++m2) oo += s_emb[m2] * Wo[m2 * 64 + o];
    s_op[mc * 64 + o] = oo;
  }
  __syncthreads();
  if (t < 64) {
    float r = bo[t];
#pragma unroll
    for (int w = 0; w < 8; ++w) r += s_op[w * 64 + t];
    out[i * 64 + t] = r;
  }
}

extern "C" void kernel_launch(void* const* d_in, const int* in_sizes, int n_in,
                              void* d_out, int out_size, void* d_ws, size_t ws_size,
                              hipStream_t stream) {
  const float* x  = (const float*)d_in[0];
  const float* e  = (const float*)d_in[1];
  const float* Wq = (const float*)d_in[2];
  const float* Wk = (const float*)d_in[3];
  const float* Wv = (const float*)d_in[4];
  const float* We = (const float*)d_in[5];
  const float* Wo = (const float*)d_in[6];
  const float* bo = (const float*)d_in[7];
  float* out = (float*)d_out;

  hipLaunchKernelGGL(fused_kernel, dim3(512), dim3(512), 0, stream,
                     e, x, Wq, Wk, We, Wv, Wo, bo, out);
}